// Round 1
// baseline (904.019 us; speedup 1.0000x reference)
//
#include <hip/hip_runtime.h>

#define N_NODES 50000
#define N_EDGES 600000
#define HID 128
#define N_LAYERS 5
#define GROWS 16

// ---------------- CSR build ----------------

__global__ void deg_count(const int* __restrict__ dst, int* __restrict__ deg) {
    int e = blockIdx.x * blockDim.x + threadIdx.x;
    if (e < N_EDGES) atomicAdd(&deg[dst[e]], 1);
}

__global__ __launch_bounds__(1024) void scan_build(const int* __restrict__ deg,
        int* __restrict__ row_ptr, int* __restrict__ cursor,
        float* __restrict__ deg_inv) {
    __shared__ int sdata[1024];
    int tid = threadIdx.x;
    const int CH = (N_NODES + 1023) / 1024;   // 49
    int start = tid * CH;
    int end   = min(start + CH, N_NODES);
    int sum = 0;
    for (int i = start; i < end; ++i) sum += deg[i];
    sdata[tid] = sum;
    __syncthreads();
    for (int off = 1; off < 1024; off <<= 1) {
        int v = (tid >= off) ? sdata[tid - off] : 0;
        __syncthreads();
        sdata[tid] += v;
        __syncthreads();
    }
    int run = sdata[tid] - sum;               // exclusive prefix
    for (int i = start; i < end; ++i) {
        row_ptr[i] = run;
        cursor[i]  = run;
        int d = deg[i];
        deg_inv[i] = 1.0f / (float)max(d, 1);
        run += d;
    }
    if (tid == 1023) row_ptr[N_NODES] = sdata[1023];
}

__global__ void fill_csr(const int* __restrict__ src, const int* __restrict__ dst,
                         int* __restrict__ cursor, int* __restrict__ col) {
    int e = blockIdx.x * blockDim.x + threadIdx.x;
    if (e < N_EDGES) {
        int d = dst[e];
        int pos = atomicAdd(&cursor[d], 1);
        col[pos] = src[e];
    }
}

// ---------------- mean aggregation (one wave per node) ----------------

__global__ __launch_bounds__(256) void aggregate(const float* __restrict__ h,
        const int* __restrict__ row_ptr, const int* __restrict__ col,
        const float* __restrict__ deg_inv, float* __restrict__ mean) {
    int wave = threadIdx.x >> 6;
    int lane = threadIdx.x & 63;
    int node = blockIdx.x * 4 + wave;
    if (node >= N_NODES) return;
    int beg = row_ptr[node], end = row_ptr[node + 1];
    float ax = 0.f, ay = 0.f;
    for (int e = beg; e < end; ++e) {
        int s = col[e];
        const float2 v = *(const float2*)&h[(size_t)s * HID + lane * 2];
        ax += v.x; ay += v.y;
    }
    float di = deg_inv[node];
    float2 r; r.x = ax * di; r.y = ay * di;
    *(float2*)&mean[(size_t)node * HID + lane * 2] = r;
}

// ---------------- fused GEMM: out = mean@Wl^T + b + h@Wr^T (+ReLU) ----------------
// block = 256 threads, 16 rows/block. Two phases share one padded LDS weight buffer.

__global__ __launch_bounds__(256) void gemm_fused(
        const float* __restrict__ mean, const float* __restrict__ h,
        const float* __restrict__ Wl, const float* __restrict__ Wr,
        const float* __restrict__ bias, float* __restrict__ out, int relu) {
    __shared__ float Wld[HID][HID + 4];       // +4 pad: spreads j over 8 bank groups
    __shared__ float rowbuf[GROWS][HID];
    const int t  = threadIdx.x;
    const int c0 = t & 31;                    // j = c0 + 32*c  (j distinct mod 32 per lane)
    const int rg = t >> 5;                    // 0..7 → rows {2rg, 2rg+1}
    const int row0 = blockIdx.x * GROWS;

    float accA[2][4], accB[2][4];
    #pragma unroll
    for (int r = 0; r < 2; ++r)
        #pragma unroll
        for (int c = 0; c < 4; ++c) { accA[r][c] = 0.f; accB[r][c] = 0.f; }

    // ---- phase 0: Wl + mean rows ----
    #pragma unroll
    for (int i = 0; i < 16; ++i) {
        int flat4 = t + i * 256;              // 4096 float4 = 128x128
        int j = flat4 >> 5;
        int k = (flat4 & 31) * 4;
        *(float4*)&Wld[j][k] = *(const float4*)&Wl[(size_t)flat4 * 4];
    }
    #pragma unroll
    for (int i = 0; i < 2; ++i) {
        int flat4 = t + i * 256;              // 512 float4 = 16x128
        int r = flat4 >> 5;
        int k = (flat4 & 31) * 4;
        *(float4*)&rowbuf[r][k] = *(const float4*)&mean[(size_t)(row0 + r) * HID + k];
    }
    __syncthreads();
    #pragma unroll 4
    for (int k = 0; k < HID; k += 4) {
        float4 m0 = *(const float4*)&rowbuf[2 * rg][k];
        float4 m1 = *(const float4*)&rowbuf[2 * rg + 1][k];
        #pragma unroll
        for (int c = 0; c < 4; ++c) {
            const float4 w = *(const float4*)&Wld[c0 + 32 * c][k];
            accA[0][c] += m0.x * w.x; accA[0][c] += m0.y * w.y;
            accA[0][c] += m0.z * w.z; accA[0][c] += m0.w * w.w;
            accA[1][c] += m1.x * w.x; accA[1][c] += m1.y * w.y;
            accA[1][c] += m1.z * w.z; accA[1][c] += m1.w * w.w;
        }
    }
    __syncthreads();

    // ---- phase 1: Wr + h rows ----
    #pragma unroll
    for (int i = 0; i < 16; ++i) {
        int flat4 = t + i * 256;
        int j = flat4 >> 5;
        int k = (flat4 & 31) * 4;
        *(float4*)&Wld[j][k] = *(const float4*)&Wr[(size_t)flat4 * 4];
    }
    #pragma unroll
    for (int i = 0; i < 2; ++i) {
        int flat4 = t + i * 256;
        int r = flat4 >> 5;
        int k = (flat4 & 31) * 4;
        *(float4*)&rowbuf[r][k] = *(const float4*)&h[(size_t)(row0 + r) * HID + k];
    }
    __syncthreads();
    #pragma unroll 4
    for (int k = 0; k < HID; k += 4) {
        float4 m0 = *(const float4*)&rowbuf[2 * rg][k];
        float4 m1 = *(const float4*)&rowbuf[2 * rg + 1][k];
        #pragma unroll
        for (int c = 0; c < 4; ++c) {
            const float4 w = *(const float4*)&Wld[c0 + 32 * c][k];
            accB[0][c] += m0.x * w.x; accB[0][c] += m0.y * w.y;
            accB[0][c] += m0.z * w.z; accB[0][c] += m0.w * w.w;
            accB[1][c] += m1.x * w.x; accB[1][c] += m1.y * w.y;
            accB[1][c] += m1.z * w.z; accB[1][c] += m1.w * w.w;
        }
    }

    // ---- epilogue (safe in-place: h rows were staged before this point) ----
    #pragma unroll
    for (int r = 0; r < 2; ++r) {
        int row = row0 + 2 * rg + r;
        #pragma unroll
        for (int c = 0; c < 4; ++c) {
            int j = c0 + 32 * c;
            float v = accA[r][c] + accB[r][c] + bias[j];
            if (relu) v = fmaxf(v, 0.f);
            out[(size_t)row * HID + j] = v;
        }
    }
}

// ---------------- launch ----------------

extern "C" void kernel_launch(void* const* d_in, const int* in_sizes, int n_in,
                              void* d_out, int out_size, void* d_ws, size_t ws_size,
                              hipStream_t stream) {
    const float* x    = (const float*)d_in[0];
    const int*   edge = (const int*)d_in[1];       // [2, E] int32
    const float* Wl   = (const float*)d_in[2];     // [5,128,128]
    const float* Wr   = (const float*)d_in[3];
    const float* bias = (const float*)d_in[4];     // [5,128]
    float* out = (float*)d_out;

    float* hbuf    = (float*)d_ws;                               // 25.6 MB
    float* mean    = hbuf + (size_t)N_NODES * HID;               // 25.6 MB
    float* deg_inv = mean + (size_t)N_NODES * HID;               // 200 KB
    int*   deg     = (int*)(deg_inv + N_NODES);                  // 200 KB
    int*   row_ptr = deg + N_NODES;                              // 200 KB
    int*   cursor  = row_ptr + (N_NODES + 1);                    // 200 KB
    int*   colarr  = cursor + N_NODES;                           // 2.4 MB

    const int* src = edge;
    const int* dst = edge + N_EDGES;

    hipMemsetAsync(deg, 0, N_NODES * sizeof(int), stream);
    deg_count<<<(N_EDGES + 255) / 256, 256, 0, stream>>>(dst, deg);
    scan_build<<<1, 1024, 0, stream>>>(deg, row_ptr, cursor, deg_inv);
    fill_csr<<<(N_EDGES + 255) / 256, 256, 0, stream>>>(src, dst, cursor, colarr);

    hipMemcpyAsync(hbuf, x, (size_t)N_NODES * HID * sizeof(float),
                   hipMemcpyDeviceToDevice, stream);

    for (int l = 0; l < N_LAYERS; ++l) {
        aggregate<<<(N_NODES + 3) / 4, 256, 0, stream>>>(hbuf, row_ptr, colarr,
                                                         deg_inv, mean);
        gemm_fused<<<N_NODES / GROWS, 256, 0, stream>>>(
            mean, hbuf,
            Wl + (size_t)l * HID * HID, Wr + (size_t)l * HID * HID,
            bias + (size_t)l * HID,
            (l == N_LAYERS - 1) ? out : hbuf,
            (l < N_LAYERS - 1) ? 1 : 0);
    }
}

// Round 2
// 682.430 us; speedup vs baseline: 1.3247x; 1.3247x over previous
//
#include <hip/hip_runtime.h>

#define N_NODES 50000
#define N_EDGES 600000
#define HID 128
#define N_LAYERS 5
#define GROWS 16
#define SCAN_BLK 256
#define N_SCAN_BLOCKS ((N_NODES + SCAN_BLK - 1) / SCAN_BLK)   // 196

// ---------------- CSR build ----------------

__global__ void deg_count(const int* __restrict__ dst, int* __restrict__ deg) {
    int e = blockIdx.x * blockDim.x + threadIdx.x;
    if (e < N_EDGES) atomicAdd(&deg[dst[e]], 1);
}

// Stage A: per-block degree sums
__global__ __launch_bounds__(SCAN_BLK) void deg_reduce(const int* __restrict__ deg,
                                                       int* __restrict__ block_sums) {
    __shared__ int s[SCAN_BLK];
    int i = blockIdx.x * SCAN_BLK + threadIdx.x;
    int v = (i < N_NODES) ? deg[i] : 0;
    s[threadIdx.x] = v;
    __syncthreads();
    for (int off = SCAN_BLK / 2; off > 0; off >>= 1) {
        if (threadIdx.x < off) s[threadIdx.x] += s[threadIdx.x + off];
        __syncthreads();
    }
    if (threadIdx.x == 0) block_sums[blockIdx.x] = s[0];
}

// Stage B: exclusive scan of the 196 block sums (one tiny block)
__global__ __launch_bounds__(SCAN_BLK) void scan_partials(const int* __restrict__ block_sums,
                                                          int* __restrict__ block_off) {
    __shared__ int s[SCAN_BLK];
    int t = threadIdx.x;
    int v = (t < N_SCAN_BLOCKS) ? block_sums[t] : 0;
    s[t] = v;
    __syncthreads();
    for (int off = 1; off < SCAN_BLK; off <<= 1) {
        int u = (t >= off) ? s[t - off] : 0;
        __syncthreads();
        s[t] += u;
        __syncthreads();
    }
    if (t < N_SCAN_BLOCKS) block_off[t] = s[t] - v;   // exclusive
}

// Stage C: block-local inclusive scan + global offset -> row_ptr/cursor/deg_inv
__global__ __launch_bounds__(SCAN_BLK) void scan_write(const int* __restrict__ deg,
        const int* __restrict__ block_off, int* __restrict__ row_ptr,
        int* __restrict__ cursor, float* __restrict__ deg_inv) {
    __shared__ int s[SCAN_BLK];
    int t = threadIdx.x;
    int i = blockIdx.x * SCAN_BLK + t;
    int v = (i < N_NODES) ? deg[i] : 0;
    s[t] = v;
    __syncthreads();
    for (int off = 1; off < SCAN_BLK; off <<= 1) {
        int u = (t >= off) ? s[t - off] : 0;
        __syncthreads();
        s[t] += u;
        __syncthreads();
    }
    int excl = s[t] - v + block_off[blockIdx.x];
    if (i < N_NODES) {
        row_ptr[i] = excl;
        cursor[i]  = excl;
        deg_inv[i] = 1.0f / (float)max(v, 1);
    }
    if (i == N_NODES) row_ptr[N_NODES] = excl;  // i==50000 exists (196*256=50176), v=0 there
}

__global__ void fill_csr(const int* __restrict__ src, const int* __restrict__ dst,
                         int* __restrict__ cursor, int* __restrict__ col) {
    int e = blockIdx.x * blockDim.x + threadIdx.x;
    if (e < N_EDGES) {
        int d = dst[e];
        int pos = atomicAdd(&cursor[d], 1);
        col[pos] = src[e];
    }
}

// ---------------- mean aggregation (one wave per node) ----------------

__global__ __launch_bounds__(256) void aggregate(const float* __restrict__ h,
        const int* __restrict__ row_ptr, const int* __restrict__ col,
        const float* __restrict__ deg_inv, float* __restrict__ mean) {
    int wave = threadIdx.x >> 6;
    int lane = threadIdx.x & 63;
    int node = blockIdx.x * 4 + wave;
    if (node >= N_NODES) return;
    int beg = row_ptr[node], end = row_ptr[node + 1];
    float ax = 0.f, ay = 0.f;
    int e = beg;
    // 2-deep unroll for memory-level parallelism on the col->row chain
    for (; e + 1 < end; e += 2) {
        int s0 = col[e], s1 = col[e + 1];
        const float2 v0 = *(const float2*)&h[(size_t)s0 * HID + lane * 2];
        const float2 v1 = *(const float2*)&h[(size_t)s1 * HID + lane * 2];
        ax += v0.x + v1.x; ay += v0.y + v1.y;
    }
    if (e < end) {
        int s0 = col[e];
        const float2 v0 = *(const float2*)&h[(size_t)s0 * HID + lane * 2];
        ax += v0.x; ay += v0.y;
    }
    float di = deg_inv[node];
    float2 r; r.x = ax * di; r.y = ay * di;
    *(float2*)&mean[(size_t)node * HID + lane * 2] = r;
}

// ---------------- fused GEMM: out = mean@Wl^T + b + h@Wr^T (+ReLU) ----------------

__global__ __launch_bounds__(256) void gemm_fused(
        const float* __restrict__ mean, const float* __restrict__ h,
        const float* __restrict__ Wl, const float* __restrict__ Wr,
        const float* __restrict__ bias, float* __restrict__ out, int relu) {
    __shared__ float Wld[HID][HID + 4];
    __shared__ float rowbuf[GROWS][HID];
    const int t  = threadIdx.x;
    const int c0 = t & 31;
    const int rg = t >> 5;
    const int row0 = blockIdx.x * GROWS;

    float accA[2][4], accB[2][4];
    #pragma unroll
    for (int r = 0; r < 2; ++r)
        #pragma unroll
        for (int c = 0; c < 4; ++c) { accA[r][c] = 0.f; accB[r][c] = 0.f; }

    // ---- phase 0: Wl + mean rows ----
    #pragma unroll
    for (int i = 0; i < 16; ++i) {
        int flat4 = t + i * 256;
        int j = flat4 >> 5;
        int k = (flat4 & 31) * 4;
        *(float4*)&Wld[j][k] = *(const float4*)&Wl[(size_t)flat4 * 4];
    }
    #pragma unroll
    for (int i = 0; i < 2; ++i) {
        int flat4 = t + i * 256;
        int r = flat4 >> 5;
        int k = (flat4 & 31) * 4;
        *(float4*)&rowbuf[r][k] = *(const float4*)&mean[(size_t)(row0 + r) * HID + k];
    }
    __syncthreads();
    #pragma unroll 4
    for (int k = 0; k < HID; k += 4) {
        float4 m0 = *(const float4*)&rowbuf[2 * rg][k];
        float4 m1 = *(const float4*)&rowbuf[2 * rg + 1][k];
        #pragma unroll
        for (int c = 0; c < 4; ++c) {
            const float4 w = *(const float4*)&Wld[c0 + 32 * c][k];
            accA[0][c] += m0.x * w.x; accA[0][c] += m0.y * w.y;
            accA[0][c] += m0.z * w.z; accA[0][c] += m0.w * w.w;
            accA[1][c] += m1.x * w.x; accA[1][c] += m1.y * w.y;
            accA[1][c] += m1.z * w.z; accA[1][c] += m1.w * w.w;
        }
    }
    __syncthreads();

    // ---- phase 1: Wr + h rows ----
    #pragma unroll
    for (int i = 0; i < 16; ++i) {
        int flat4 = t + i * 256;
        int j = flat4 >> 5;
        int k = (flat4 & 31) * 4;
        *(float4*)&Wld[j][k] = *(const float4*)&Wr[(size_t)flat4 * 4];
    }
    #pragma unroll
    for (int i = 0; i < 2; ++i) {
        int flat4 = t + i * 256;
        int r = flat4 >> 5;
        int k = (flat4 & 31) * 4;
        *(float4*)&rowbuf[r][k] = *(const float4*)&h[(size_t)(row0 + r) * HID + k];
    }
    __syncthreads();
    #pragma unroll 4
    for (int k = 0; k < HID; k += 4) {
        float4 m0 = *(const float4*)&rowbuf[2 * rg][k];
        float4 m1 = *(const float4*)&rowbuf[2 * rg + 1][k];
        #pragma unroll
        for (int c = 0; c < 4; ++c) {
            const float4 w = *(const float4*)&Wld[c0 + 32 * c][k];
            accB[0][c] += m0.x * w.x; accB[0][c] += m0.y * w.y;
            accB[0][c] += m0.z * w.z; accB[0][c] += m0.w * w.w;
            accB[1][c] += m1.x * w.x; accB[1][c] += m1.y * w.y;
            accB[1][c] += m1.z * w.z; accB[1][c] += m1.w * w.w;
        }
    }

    #pragma unroll
    for (int r = 0; r < 2; ++r) {
        int row = row0 + 2 * rg + r;
        #pragma unroll
        for (int c = 0; c < 4; ++c) {
            int j = c0 + 32 * c;
            float v = accA[r][c] + accB[r][c] + bias[j];
            if (relu) v = fmaxf(v, 0.f);
            out[(size_t)row * HID + j] = v;
        }
    }
}

// ---------------- launch ----------------

extern "C" void kernel_launch(void* const* d_in, const int* in_sizes, int n_in,
                              void* d_out, int out_size, void* d_ws, size_t ws_size,
                              hipStream_t stream) {
    const float* x    = (const float*)d_in[0];
    const int*   edge = (const int*)d_in[1];       // [2, E] int
    const float* Wl   = (const float*)d_in[2];     // [5,128,128]
    const float* Wr   = (const float*)d_in[3];
    const float* bias = (const float*)d_in[4];     // [5,128]
    float* out = (float*)d_out;

    float* hbuf     = (float*)d_ws;                              // 25.6 MB
    float* mean     = hbuf + (size_t)N_NODES * HID;              // 25.6 MB
    float* deg_inv  = mean + (size_t)N_NODES * HID;              // 200 KB
    int*   deg      = (int*)(deg_inv + N_NODES);                 // 200 KB
    int*   row_ptr  = deg + N_NODES;                             // 200 KB
    int*   cursor   = row_ptr + (N_NODES + 1);                   // 200 KB
    int*   colarr   = cursor + N_NODES;                          // 2.4 MB
    int*   blk_sums = colarr + N_EDGES;                          // 784 B
    int*   blk_off  = blk_sums + N_SCAN_BLOCKS;                  // 784 B

    const int* src = edge;
    const int* dst = edge + N_EDGES;

    hipMemsetAsync(deg, 0, N_NODES * sizeof(int), stream);
    deg_count<<<(N_EDGES + 255) / 256, 256, 0, stream>>>(dst, deg);
    deg_reduce<<<N_SCAN_BLOCKS, SCAN_BLK, 0, stream>>>(deg, blk_sums);
    scan_partials<<<1, SCAN_BLK, 0, stream>>>(blk_sums, blk_off);
    scan_write<<<N_SCAN_BLOCKS, SCAN_BLK, 0, stream>>>(deg, blk_off, row_ptr,
                                                       cursor, deg_inv);
    fill_csr<<<(N_EDGES + 255) / 256, 256, 0, stream>>>(src, dst, cursor, colarr);

    for (int l = 0; l < N_LAYERS; ++l) {
        const float* hin = (l == 0) ? x : hbuf;
        aggregate<<<(N_NODES + 3) / 4, 256, 0, stream>>>(hin, row_ptr, colarr,
                                                         deg_inv, mean);
        gemm_fused<<<N_NODES / GROWS, 256, 0, stream>>>(
            mean, hin,
            Wl + (size_t)l * HID * HID, Wr + (size_t)l * HID * HID,
            bias + (size_t)l * HID,
            (l == N_LAYERS - 1) ? out : hbuf,
            (l < N_LAYERS - 1) ? 1 : 0);
    }
}

// Round 3
// 439.030 us; speedup vs baseline: 2.0591x; 1.5544x over previous
//
#include <hip/hip_runtime.h>

#define N_NODES 50000
#define N_EDGES 600000
#define HID 128
#define N_LAYERS 5
#define SCAN_BLK 256
#define N_SCAN_BLOCKS ((N_NODES + SCAN_BLK - 1) / SCAN_BLK)   // 196
#define NH ((size_t)N_NODES * HID)

typedef _Float16 half8 __attribute__((ext_vector_type(8)));
typedef _Float16 half4 __attribute__((ext_vector_type(4)));
typedef _Float16 half2v __attribute__((ext_vector_type(2)));
typedef float f32x4 __attribute__((ext_vector_type(4)));

// ---------------- CSR build ----------------

__global__ void deg_count(const int* __restrict__ dst, int* __restrict__ deg) {
    int e = blockIdx.x * blockDim.x + threadIdx.x;
    if (e < N_EDGES) atomicAdd(&deg[dst[e]], 1);
}

__global__ __launch_bounds__(SCAN_BLK) void deg_reduce(const int* __restrict__ deg,
                                                       int* __restrict__ block_sums) {
    __shared__ int s[SCAN_BLK];
    int i = blockIdx.x * SCAN_BLK + threadIdx.x;
    int v = (i < N_NODES) ? deg[i] : 0;
    s[threadIdx.x] = v;
    __syncthreads();
    for (int off = SCAN_BLK / 2; off > 0; off >>= 1) {
        if (threadIdx.x < off) s[threadIdx.x] += s[threadIdx.x + off];
        __syncthreads();
    }
    if (threadIdx.x == 0) block_sums[blockIdx.x] = s[0];
}

__global__ __launch_bounds__(SCAN_BLK) void scan_partials(const int* __restrict__ block_sums,
                                                          int* __restrict__ block_off) {
    __shared__ int s[SCAN_BLK];
    int t = threadIdx.x;
    int v = (t < N_SCAN_BLOCKS) ? block_sums[t] : 0;
    s[t] = v;
    __syncthreads();
    for (int off = 1; off < SCAN_BLK; off <<= 1) {
        int u = (t >= off) ? s[t - off] : 0;
        __syncthreads();
        s[t] += u;
        __syncthreads();
    }
    if (t < N_SCAN_BLOCKS) block_off[t] = s[t] - v;
}

__global__ __launch_bounds__(SCAN_BLK) void scan_write(const int* __restrict__ deg,
        const int* __restrict__ block_off, int* __restrict__ row_ptr,
        int* __restrict__ cursor, float* __restrict__ deg_inv) {
    __shared__ int s[SCAN_BLK];
    int t = threadIdx.x;
    int i = blockIdx.x * SCAN_BLK + t;
    int v = (i < N_NODES) ? deg[i] : 0;
    s[t] = v;
    __syncthreads();
    for (int off = 1; off < SCAN_BLK; off <<= 1) {
        int u = (t >= off) ? s[t - off] : 0;
        __syncthreads();
        s[t] += u;
        __syncthreads();
    }
    int excl = s[t] - v + block_off[blockIdx.x];
    if (i < N_NODES) {
        row_ptr[i] = excl;
        cursor[i]  = excl;
        deg_inv[i] = 1.0f / (float)max(v, 1);
    }
    if (i == N_NODES) row_ptr[N_NODES] = excl;
}

__global__ void fill_csr(const int* __restrict__ src, const int* __restrict__ dst,
                         int* __restrict__ cursor, int* __restrict__ col) {
    int e = blockIdx.x * blockDim.x + threadIdx.x;
    if (e < N_EDGES) {
        int d = dst[e];
        int pos = atomicAdd(&cursor[d], 1);
        col[pos] = src[e];
    }
}

// ---------------- fp32 -> fp16 hi/lo split (error-compensated pair) ----------------

__global__ void split_f32(const float* __restrict__ src,
                          _Float16* __restrict__ hi, _Float16* __restrict__ lo, int n4) {
    int i = blockIdx.x * blockDim.x + threadIdx.x;
    if (i >= n4) return;
    float4 v = *(const float4*)(src + (size_t)i * 4);
    half4 h, l;
    h.x = (_Float16)v.x; l.x = (_Float16)(v.x - (float)h.x);
    h.y = (_Float16)v.y; l.y = (_Float16)(v.y - (float)h.y);
    h.z = (_Float16)v.z; l.z = (_Float16)(v.z - (float)h.z);
    h.w = (_Float16)v.w; l.w = (_Float16)(v.w - (float)h.w);
    *(half4*)(hi + (size_t)i * 4) = h;
    *(half4*)(lo + (size_t)i * 4) = l;
}

// ---------------- mean aggregation (one wave per node, split in/out) ----------------

__global__ __launch_bounds__(256) void aggregate_split(
        const _Float16* __restrict__ h_hi, const _Float16* __restrict__ h_lo,
        const int* __restrict__ row_ptr, const int* __restrict__ col,
        const float* __restrict__ deg_inv,
        _Float16* __restrict__ mean_hi, _Float16* __restrict__ mean_lo) {
    int wave = threadIdx.x >> 6;
    int lane = threadIdx.x & 63;
    int node = blockIdx.x * 4 + wave;
    if (node >= N_NODES) return;
    int beg = row_ptr[node], end = row_ptr[node + 1];
    const int off = lane * 2;
    float ax = 0.f, ay = 0.f;
    int e = beg;
    for (; e + 1 < end; e += 2) {
        int s0 = col[e], s1 = col[e + 1];
        half2v a0 = *(const half2v*)(h_hi + (size_t)s0 * HID + off);
        half2v b0 = *(const half2v*)(h_lo + (size_t)s0 * HID + off);
        half2v a1 = *(const half2v*)(h_hi + (size_t)s1 * HID + off);
        half2v b1 = *(const half2v*)(h_lo + (size_t)s1 * HID + off);
        ax += (float)a0.x + (float)b0.x + (float)a1.x + (float)b1.x;
        ay += (float)a0.y + (float)b0.y + (float)a1.y + (float)b1.y;
    }
    if (e < end) {
        int s0 = col[e];
        half2v a0 = *(const half2v*)(h_hi + (size_t)s0 * HID + off);
        half2v b0 = *(const half2v*)(h_lo + (size_t)s0 * HID + off);
        ax += (float)a0.x + (float)b0.x;
        ay += (float)a0.y + (float)b0.y;
    }
    float di = deg_inv[node];
    float mx = ax * di, my = ay * di;
    _Float16 hx = (_Float16)mx, lx = (_Float16)(mx - (float)hx);
    _Float16 hy = (_Float16)my, ly = (_Float16)(my - (float)hy);
    half2v hv; hv.x = hx; hv.y = hy;
    half2v lv; lv.x = lx; lv.y = ly;
    *(half2v*)(mean_hi + (size_t)node * HID + off) = hv;
    *(half2v*)(mean_lo + (size_t)node * HID + off) = lv;
}

// ---------------- MFMA GEMM: out = mean@Wl^T + b + h@Wr^T (+ReLU / final fp32) ----
// fp16-split: acc += Ah@Wh + Al@Wh + Ah@Wl for each of the two products.
// 512 thr = 8 waves; wave handles 32 rows (2 x 16-row tiles), all 128 cols.
// Weights (4 matrices x 32KB fp16) staged into XOR-swizzled LDS once per block.

__global__ __launch_bounds__(512, 2) void gemm_mfma(
        const _Float16* __restrict__ mean_hi, const _Float16* __restrict__ mean_lo,
        const _Float16* __restrict__ h_hi,    const _Float16* __restrict__ h_lo,
        const _Float16* __restrict__ Wlh, const _Float16* __restrict__ Wll,
        const _Float16* __restrict__ Wrh, const _Float16* __restrict__ Wrl,
        const float* __restrict__ bias,
        _Float16* __restrict__ oh_hi, _Float16* __restrict__ oh_lo,
        float* __restrict__ out_f32, int final_layer) {
    __shared__ char Wlds[131072];          // [4 mats][128 j][128 k] fp16, swizzled
    const int t    = threadIdx.x;
    const int lane = t & 63;
    const int w    = t >> 6;
    const int jr   = lane & 15;            // A-row / W-row / C-col index within tile
    const int q    = lane >> 4;            // k-quadrant / C-row quadrant

    // ---- stage weights with 16B-granule XOR swizzle (pos ^= j&7) ----
    #pragma unroll
    for (int i = 0; i < 4; ++i) {
        int gi = t + i * 512;              // granule 0..2047 within one matrix
        int j = gi >> 4, p = gi & 15;
        int dstb = j * 256 + (p ^ (j & 7)) * 16;
        int srci = j * HID + p * 8;
        *(half8*)&Wlds[0 * 32768 + dstb] = *(const half8*)(Wlh + srci);
        *(half8*)&Wlds[1 * 32768 + dstb] = *(const half8*)(Wll + srci);
        *(half8*)&Wlds[2 * 32768 + dstb] = *(const half8*)(Wrh + srci);
        *(half8*)&Wlds[3 * 32768 + dstb] = *(const half8*)(Wrl + srci);
    }
    __syncthreads();

    const int base0 = blockIdx.x * 256 + w * 32;
    int r0 = base0 + jr;      if (r0 > N_NODES - 1) r0 = N_NODES - 1;
    int r1 = base0 + 16 + jr; if (r1 > N_NODES - 1) r1 = N_NODES - 1;
    const int ko = q * 8;

    f32x4 acc0[8], acc1[8];
    #pragma unroll
    for (int jt = 0; jt < 8; ++jt) {
        acc0[jt] = (f32x4)(0.f);
        acc1[jt] = (f32x4)(0.f);
    }

    #pragma unroll 2
    for (int kk = 0; kk < 4; ++kk) {
        const size_t a0 = (size_t)r0 * HID + kk * 32 + ko;
        const size_t a1 = (size_t)r1 * HID + kk * 32 + ko;
        half8 mh0 = *(const half8*)(mean_hi + a0);
        half8 ml0 = *(const half8*)(mean_lo + a0);
        half8 hh0 = *(const half8*)(h_hi   + a0);
        half8 hl0 = *(const half8*)(h_lo   + a0);
        half8 mh1 = *(const half8*)(mean_hi + a1);
        half8 ml1 = *(const half8*)(mean_lo + a1);
        half8 hh1 = *(const half8*)(h_hi   + a1);
        half8 hl1 = *(const half8*)(h_lo   + a1);
        #pragma unroll
        for (int jt = 0; jt < 8; ++jt) {
            int j  = jt * 16 + jr;
            int wb = j * 256 + (((kk * 4 + q) ^ (j & 7)) * 16);
            half8 wlh = *(const half8*)&Wlds[0 * 32768 + wb];
            half8 wll = *(const half8*)&Wlds[1 * 32768 + wb];
            half8 wrh = *(const half8*)&Wlds[2 * 32768 + wb];
            half8 wrl = *(const half8*)&Wlds[3 * 32768 + wb];
            acc0[jt] = __builtin_amdgcn_mfma_f32_16x16x32_f16(mh0, wlh, acc0[jt], 0, 0, 0);
            acc0[jt] = __builtin_amdgcn_mfma_f32_16x16x32_f16(ml0, wlh, acc0[jt], 0, 0, 0);
            acc0[jt] = __builtin_amdgcn_mfma_f32_16x16x32_f16(mh0, wll, acc0[jt], 0, 0, 0);
            acc0[jt] = __builtin_amdgcn_mfma_f32_16x16x32_f16(hh0, wrh, acc0[jt], 0, 0, 0);
            acc0[jt] = __builtin_amdgcn_mfma_f32_16x16x32_f16(hl0, wrh, acc0[jt], 0, 0, 0);
            acc0[jt] = __builtin_amdgcn_mfma_f32_16x16x32_f16(hh0, wrl, acc0[jt], 0, 0, 0);
            acc1[jt] = __builtin_amdgcn_mfma_f32_16x16x32_f16(mh1, wlh, acc1[jt], 0, 0, 0);
            acc1[jt] = __builtin_amdgcn_mfma_f32_16x16x32_f16(ml1, wlh, acc1[jt], 0, 0, 0);
            acc1[jt] = __builtin_amdgcn_mfma_f32_16x16x32_f16(mh1, wll, acc1[jt], 0, 0, 0);
            acc1[jt] = __builtin_amdgcn_mfma_f32_16x16x32_f16(hh1, wrh, acc1[jt], 0, 0, 0);
            acc1[jt] = __builtin_amdgcn_mfma_f32_16x16x32_f16(hl1, wrh, acc1[jt], 0, 0, 0);
            acc1[jt] = __builtin_amdgcn_mfma_f32_16x16x32_f16(hh1, wrl, acc1[jt], 0, 0, 0);
        }
    }

    // ---- epilogue: C/D map row=(lane>>4)*4+g, col=lane&15 ----
    float bv[8];
    #pragma unroll
    for (int jt = 0; jt < 8; ++jt) bv[jt] = bias[jt * 16 + jr];

    #pragma unroll
    for (int jt = 0; jt < 8; ++jt) {
        #pragma unroll
        for (int g = 0; g < 4; ++g) {
            int row = base0 + q * 4 + g;
            if (row < N_NODES) {
                float v = acc0[jt][g] + bv[jt];
                size_t idx = (size_t)row * HID + jt * 16 + jr;
                if (final_layer) {
                    out_f32[idx] = v;
                } else {
                    v = fmaxf(v, 0.f);
                    _Float16 hi = (_Float16)v;
                    oh_hi[idx] = hi;
                    oh_lo[idx] = (_Float16)(v - (float)hi);
                }
            }
            int row2 = base0 + 16 + q * 4 + g;
            if (row2 < N_NODES) {
                float v = acc1[jt][g] + bv[jt];
                size_t idx = (size_t)row2 * HID + jt * 16 + jr;
                if (final_layer) {
                    out_f32[idx] = v;
                } else {
                    v = fmaxf(v, 0.f);
                    _Float16 hi = (_Float16)v;
                    oh_hi[idx] = hi;
                    oh_lo[idx] = (_Float16)(v - (float)hi);
                }
            }
        }
    }
}

// ---------------- launch ----------------

extern "C" void kernel_launch(void* const* d_in, const int* in_sizes, int n_in,
                              void* d_out, int out_size, void* d_ws, size_t ws_size,
                              hipStream_t stream) {
    const float* x    = (const float*)d_in[0];
    const int*   edge = (const int*)d_in[1];
    const float* Wl   = (const float*)d_in[2];
    const float* Wr   = (const float*)d_in[3];
    const float* bias = (const float*)d_in[4];
    float* out = (float*)d_out;

    _Float16* h_hi    = (_Float16*)d_ws;          // 12.8 MB each
    _Float16* h_lo    = h_hi + NH;
    _Float16* mean_hi = h_lo + NH;
    _Float16* mean_lo = mean_hi + NH;
    _Float16* Wlh     = mean_lo + NH;              // 5*128*128 fp16 each
    _Float16* Wll     = Wlh + 81920;
    _Float16* Wrh     = Wll + 81920;
    _Float16* Wrl     = Wrh + 81920;
    float* deg_inv    = (float*)(Wrl + 81920);
    int*   deg        = (int*)(deg_inv + N_NODES);
    int*   row_ptr    = deg + N_NODES;
    int*   cursor     = row_ptr + (N_NODES + 1);
    int*   colarr     = cursor + N_NODES;
    int*   blk_sums   = colarr + N_EDGES;
    int*   blk_off    = blk_sums + N_SCAN_BLOCKS;

    const int* src = edge;
    const int* dst = edge + N_EDGES;

    hipMemsetAsync(deg, 0, N_NODES * sizeof(int), stream);
    deg_count<<<(N_EDGES + 255) / 256, 256, 0, stream>>>(dst, deg);
    deg_reduce<<<N_SCAN_BLOCKS, SCAN_BLK, 0, stream>>>(deg, blk_sums);
    scan_partials<<<1, SCAN_BLK, 0, stream>>>(blk_sums, blk_off);
    scan_write<<<N_SCAN_BLOCKS, SCAN_BLK, 0, stream>>>(deg, blk_off, row_ptr,
                                                       cursor, deg_inv);
    fill_csr<<<(N_EDGES + 255) / 256, 256, 0, stream>>>(src, dst, cursor, colarr);

    split_f32<<<(20480 + 255) / 256, 256, 0, stream>>>(Wl, Wlh, Wll, 20480);
    split_f32<<<(20480 + 255) / 256, 256, 0, stream>>>(Wr, Wrh, Wrl, 20480);
    split_f32<<<(1638400 + 255) / 256, 256, 0, stream>>>(x, h_hi, h_lo, 1638400);

    for (int l = 0; l < N_LAYERS; ++l) {
        aggregate_split<<<(N_NODES + 3) / 4, 256, 0, stream>>>(
            h_hi, h_lo, row_ptr, colarr, deg_inv, mean_hi, mean_lo);
        gemm_mfma<<<(N_NODES + 255) / 256, 512, 0, stream>>>(
            mean_hi, mean_lo, h_hi, h_lo,
            Wlh + (size_t)l * 16384, Wll + (size_t)l * 16384,
            Wrh + (size_t)l * 16384, Wrl + (size_t)l * 16384,
            bias + (size_t)l * HID,
            h_hi, h_lo, out, (l == N_LAYERS - 1) ? 1 : 0);
    }
}

// Round 4
// 412.224 us; speedup vs baseline: 2.1930x; 1.0650x over previous
//
#include <hip/hip_runtime.h>

#define N_NODES 50000
#define N_EDGES 600000
#define HID 128
#define N_LAYERS 5
#define SCAN_BLK 256
#define N_SCAN_BLOCKS ((N_NODES + SCAN_BLK - 1) / SCAN_BLK)   // 196
#define NH ((size_t)N_NODES * HID)

typedef unsigned int u32;
typedef _Float16 half8 __attribute__((ext_vector_type(8)));
typedef _Float16 half4 __attribute__((ext_vector_type(4)));
typedef float f32x4 __attribute__((ext_vector_type(4)));
typedef u32 u32x8 __attribute__((ext_vector_type(8)));

// packed split format: one u32 per feature; h[0]=fp16 hi, h[1]=fp16 residual
union PK { u32 u; _Float16 h[2]; };

__device__ inline u32 pack_split(float v) {
    PK r;
    r.h[0] = (_Float16)v;
    r.h[1] = (_Float16)(v - (float)r.h[0]);
    return r.u;
}
__device__ inline float unpack_sum(u32 p) {
    PK r; r.u = p;
    return (float)r.h[0] + (float)r.h[1];
}

// ---------------- CSR build ----------------

__global__ void deg_count(const int* __restrict__ dst, int* __restrict__ deg) {
    int e = blockIdx.x * blockDim.x + threadIdx.x;
    if (e < N_EDGES) atomicAdd(&deg[dst[e]], 1);
}

__global__ __launch_bounds__(SCAN_BLK) void deg_reduce(const int* __restrict__ deg,
                                                       int* __restrict__ block_sums) {
    __shared__ int s[SCAN_BLK];
    int i = blockIdx.x * SCAN_BLK + threadIdx.x;
    int v = (i < N_NODES) ? deg[i] : 0;
    s[threadIdx.x] = v;
    __syncthreads();
    for (int off = SCAN_BLK / 2; off > 0; off >>= 1) {
        if (threadIdx.x < off) s[threadIdx.x] += s[threadIdx.x + off];
        __syncthreads();
    }
    if (threadIdx.x == 0) block_sums[blockIdx.x] = s[0];
}

__global__ __launch_bounds__(SCAN_BLK) void scan_partials(const int* __restrict__ block_sums,
                                                          int* __restrict__ block_off) {
    __shared__ int s[SCAN_BLK];
    int t = threadIdx.x;
    int v = (t < N_SCAN_BLOCKS) ? block_sums[t] : 0;
    s[t] = v;
    __syncthreads();
    for (int off = 1; off < SCAN_BLK; off <<= 1) {
        int u = (t >= off) ? s[t - off] : 0;
        __syncthreads();
        s[t] += u;
        __syncthreads();
    }
    if (t < N_SCAN_BLOCKS) block_off[t] = s[t] - v;
}

__global__ __launch_bounds__(SCAN_BLK) void scan_write(const int* __restrict__ deg,
        const int* __restrict__ block_off, int* __restrict__ row_ptr,
        int* __restrict__ cursor, float* __restrict__ deg_inv) {
    __shared__ int s[SCAN_BLK];
    int t = threadIdx.x;
    int i = blockIdx.x * SCAN_BLK + t;
    int v = (i < N_NODES) ? deg[i] : 0;
    s[t] = v;
    __syncthreads();
    for (int off = 1; off < SCAN_BLK; off <<= 1) {
        int u = (t >= off) ? s[t - off] : 0;
        __syncthreads();
        s[t] += u;
        __syncthreads();
    }
    int excl = s[t] - v + block_off[blockIdx.x];
    if (i < N_NODES) {
        row_ptr[i] = excl;
        cursor[i]  = excl;
        deg_inv[i] = 1.0f / (float)max(v, 1);
    }
    if (i == N_NODES) row_ptr[N_NODES] = excl;
}

__global__ void fill_csr(const int* __restrict__ src, const int* __restrict__ dst,
                         int* __restrict__ cursor, int* __restrict__ col) {
    int e = blockIdx.x * blockDim.x + threadIdx.x;
    if (e < N_EDGES) {
        int d = dst[e];
        int pos = atomicAdd(&cursor[d], 1);
        col[pos] = src[e];
    }
}

// ---------------- splits ----------------

// weights: separate hi/lo fp16 buffers (LDS staging layout unchanged)
__global__ void split_sep(const float* __restrict__ src,
                          _Float16* __restrict__ hi, _Float16* __restrict__ lo, int n4) {
    int i = blockIdx.x * blockDim.x + threadIdx.x;
    if (i >= n4) return;
    float4 v = *(const float4*)(src + (size_t)i * 4);
    half4 h, l;
    h.x = (_Float16)v.x; l.x = (_Float16)(v.x - (float)h.x);
    h.y = (_Float16)v.y; l.y = (_Float16)(v.y - (float)h.y);
    h.z = (_Float16)v.z; l.z = (_Float16)(v.z - (float)h.z);
    h.w = (_Float16)v.w; l.w = (_Float16)(v.w - (float)h.w);
    *(half4*)(hi + (size_t)i * 4) = h;
    *(half4*)(lo + (size_t)i * 4) = l;
}

// features: packed u32 buffer
__global__ void split_pk(const float* __restrict__ src, u32* __restrict__ dst, int n4) {
    int i = blockIdx.x * blockDim.x + threadIdx.x;
    if (i >= n4) return;
    float4 v = *(const float4*)(src + (size_t)i * 4);
    uint4 r;
    r.x = pack_split(v.x); r.y = pack_split(v.y);
    r.z = pack_split(v.z); r.w = pack_split(v.w);
    *(uint4*)(dst + (size_t)i * 4) = r;
}

// ---------------- mean aggregation (one wave per node, packed, 4-deep MLP) -------

__global__ __launch_bounds__(256) void aggregate_pk(const u32* __restrict__ hp,
        const int* __restrict__ row_ptr, const int* __restrict__ col,
        const float* __restrict__ deg_inv, u32* __restrict__ mp) {
    int wave = threadIdx.x >> 6;
    int lane = threadIdx.x & 63;
    int node = blockIdx.x * 4 + wave;
    if (node >= N_NODES) return;
    int beg = row_ptr[node], end = row_ptr[node + 1];
    const int off = lane * 2;
    float ax = 0.f, ay = 0.f;
    int e = beg;
    for (; e + 3 < end; e += 4) {
        int s0 = col[e], s1 = col[e + 1], s2 = col[e + 2], s3 = col[e + 3];
        uint2 v0 = *(const uint2*)(hp + (size_t)s0 * HID + off);
        uint2 v1 = *(const uint2*)(hp + (size_t)s1 * HID + off);
        uint2 v2 = *(const uint2*)(hp + (size_t)s2 * HID + off);
        uint2 v3 = *(const uint2*)(hp + (size_t)s3 * HID + off);
        ax += unpack_sum(v0.x) + unpack_sum(v1.x) + unpack_sum(v2.x) + unpack_sum(v3.x);
        ay += unpack_sum(v0.y) + unpack_sum(v1.y) + unpack_sum(v2.y) + unpack_sum(v3.y);
    }
    for (; e < end; ++e) {
        int s0 = col[e];
        uint2 v0 = *(const uint2*)(hp + (size_t)s0 * HID + off);
        ax += unpack_sum(v0.x);
        ay += unpack_sum(v0.y);
    }
    float di = deg_inv[node];
    uint2 r;
    r.x = pack_split(ax * di);
    r.y = pack_split(ay * di);
    *(uint2*)(mp + (size_t)node * HID + off) = r;
}

// ---------------- MFMA GEMM (packed A operands) ----------------

__device__ inline void unpk8(u32x8 p, half8& hi, half8& lo) {
    #pragma unroll
    for (int i = 0; i < 8; ++i) {
        PK t; t.u = p[i];
        hi[i] = t.h[0];
        lo[i] = t.h[1];
    }
}

__global__ __launch_bounds__(512, 2) void gemm_mfma(
        const u32* __restrict__ mean_pk, const u32* __restrict__ h_pk,
        const _Float16* __restrict__ Wlh, const _Float16* __restrict__ Wll,
        const _Float16* __restrict__ Wrh, const _Float16* __restrict__ Wrl,
        const float* __restrict__ bias,
        u32* __restrict__ out_pk, float* __restrict__ out_f32, int final_layer) {
    __shared__ char Wlds[131072];          // [4 mats][128 j][128 k] fp16, swizzled
    const int t    = threadIdx.x;
    const int lane = t & 63;
    const int w    = t >> 6;
    const int jr   = lane & 15;
    const int q    = lane >> 4;

    #pragma unroll
    for (int i = 0; i < 4; ++i) {
        int gi = t + i * 512;
        int j = gi >> 4, p = gi & 15;
        int dstb = j * 256 + (p ^ (j & 7)) * 16;
        int srci = j * HID + p * 8;
        *(half8*)&Wlds[0 * 32768 + dstb] = *(const half8*)(Wlh + srci);
        *(half8*)&Wlds[1 * 32768 + dstb] = *(const half8*)(Wll + srci);
        *(half8*)&Wlds[2 * 32768 + dstb] = *(const half8*)(Wrh + srci);
        *(half8*)&Wlds[3 * 32768 + dstb] = *(const half8*)(Wrl + srci);
    }
    __syncthreads();

    const int base0 = blockIdx.x * 256 + w * 32;
    int r0 = base0 + jr;      if (r0 > N_NODES - 1) r0 = N_NODES - 1;
    int r1 = base0 + 16 + jr; if (r1 > N_NODES - 1) r1 = N_NODES - 1;
    const int ko = q * 8;

    f32x4 acc0[8], acc1[8];
    #pragma unroll
    for (int jt = 0; jt < 8; ++jt) {
        acc0[jt] = (f32x4)(0.f);
        acc1[jt] = (f32x4)(0.f);
    }

    #pragma unroll 2
    for (int kk = 0; kk < 4; ++kk) {
        const size_t a0 = (size_t)r0 * HID + kk * 32 + ko;
        const size_t a1 = (size_t)r1 * HID + kk * 32 + ko;
        u32x8 mp0 = *(const u32x8*)(mean_pk + a0);
        u32x8 hp0 = *(const u32x8*)(h_pk   + a0);
        u32x8 mp1 = *(const u32x8*)(mean_pk + a1);
        u32x8 hp1 = *(const u32x8*)(h_pk   + a1);
        half8 mh0, ml0, hh0, hl0, mh1, ml1, hh1, hl1;
        unpk8(mp0, mh0, ml0); unpk8(hp0, hh0, hl0);
        unpk8(mp1, mh1, ml1); unpk8(hp1, hh1, hl1);
        #pragma unroll
        for (int jt = 0; jt < 8; ++jt) {
            int j  = jt * 16 + jr;
            int wb = j * 256 + (((kk * 4 + q) ^ (j & 7)) * 16);
            half8 wlh = *(const half8*)&Wlds[0 * 32768 + wb];
            half8 wll = *(const half8*)&Wlds[1 * 32768 + wb];
            half8 wrh = *(const half8*)&Wlds[2 * 32768 + wb];
            half8 wrl = *(const half8*)&Wlds[3 * 32768 + wb];
            acc0[jt] = __builtin_amdgcn_mfma_f32_16x16x32_f16(mh0, wlh, acc0[jt], 0, 0, 0);
            acc0[jt] = __builtin_amdgcn_mfma_f32_16x16x32_f16(ml0, wlh, acc0[jt], 0, 0, 0);
            acc0[jt] = __builtin_amdgcn_mfma_f32_16x16x32_f16(mh0, wll, acc0[jt], 0, 0, 0);
            acc0[jt] = __builtin_amdgcn_mfma_f32_16x16x32_f16(hh0, wrh, acc0[jt], 0, 0, 0);
            acc0[jt] = __builtin_amdgcn_mfma_f32_16x16x32_f16(hl0, wrh, acc0[jt], 0, 0, 0);
            acc0[jt] = __builtin_amdgcn_mfma_f32_16x16x32_f16(hh0, wrl, acc0[jt], 0, 0, 0);
            acc1[jt] = __builtin_amdgcn_mfma_f32_16x16x32_f16(mh1, wlh, acc1[jt], 0, 0, 0);
            acc1[jt] = __builtin_amdgcn_mfma_f32_16x16x32_f16(ml1, wlh, acc1[jt], 0, 0, 0);
            acc1[jt] = __builtin_amdgcn_mfma_f32_16x16x32_f16(mh1, wll, acc1[jt], 0, 0, 0);
            acc1[jt] = __builtin_amdgcn_mfma_f32_16x16x32_f16(hh1, wrh, acc1[jt], 0, 0, 0);
            acc1[jt] = __builtin_amdgcn_mfma_f32_16x16x32_f16(hl1, wrh, acc1[jt], 0, 0, 0);
            acc1[jt] = __builtin_amdgcn_mfma_f32_16x16x32_f16(hh1, wrl, acc1[jt], 0, 0, 0);
        }
    }

    float bv[8];
    #pragma unroll
    for (int jt = 0; jt < 8; ++jt) bv[jt] = bias[jt * 16 + jr];

    #pragma unroll
    for (int jt = 0; jt < 8; ++jt) {
        #pragma unroll
        for (int g = 0; g < 4; ++g) {
            int row = base0 + q * 4 + g;
            if (row < N_NODES) {
                float v = acc0[jt][g] + bv[jt];
                size_t idx = (size_t)row * HID + jt * 16 + jr;
                if (final_layer) out_f32[idx] = v;
                else             out_pk[idx] = pack_split(fmaxf(v, 0.f));
            }
            int row2 = base0 + 16 + q * 4 + g;
            if (row2 < N_NODES) {
                float v = acc1[jt][g] + bv[jt];
                size_t idx = (size_t)row2 * HID + jt * 16 + jr;
                if (final_layer) out_f32[idx] = v;
                else             out_pk[idx] = pack_split(fmaxf(v, 0.f));
            }
        }
    }
}

// ---------------- launch ----------------

extern "C" void kernel_launch(void* const* d_in, const int* in_sizes, int n_in,
                              void* d_out, int out_size, void* d_ws, size_t ws_size,
                              hipStream_t stream) {
    const float* x    = (const float*)d_in[0];
    const int*   edge = (const int*)d_in[1];
    const float* Wl   = (const float*)d_in[2];
    const float* Wr   = (const float*)d_in[3];
    const float* bias = (const float*)d_in[4];
    float* out = (float*)d_out;

    u32* h_pk    = (u32*)d_ws;                    // 25.6 MB
    u32* mean_pk = h_pk + NH;                     // 25.6 MB
    _Float16* Wlh = (_Float16*)(mean_pk + NH);    // 5*128*128 fp16 each
    _Float16* Wll = Wlh + 81920;
    _Float16* Wrh = Wll + 81920;
    _Float16* Wrl = Wrh + 81920;
    float* deg_inv = (float*)(Wrl + 81920);
    int*   deg     = (int*)(deg_inv + N_NODES);
    int*   row_ptr = deg + N_NODES;
    int*   cursor  = row_ptr + (N_NODES + 1);
    int*   colarr  = cursor + N_NODES;
    int*   blk_sums = colarr + N_EDGES;
    int*   blk_off  = blk_sums + N_SCAN_BLOCKS;

    const int* src = edge;
    const int* dst = edge + N_EDGES;

    hipMemsetAsync(deg, 0, N_NODES * sizeof(int), stream);
    deg_count<<<(N_EDGES + 255) / 256, 256, 0, stream>>>(dst, deg);
    deg_reduce<<<N_SCAN_BLOCKS, SCAN_BLK, 0, stream>>>(deg, blk_sums);
    scan_partials<<<1, SCAN_BLK, 0, stream>>>(blk_sums, blk_off);
    scan_write<<<N_SCAN_BLOCKS, SCAN_BLK, 0, stream>>>(deg, blk_off, row_ptr,
                                                       cursor, deg_inv);
    fill_csr<<<(N_EDGES + 255) / 256, 256, 0, stream>>>(src, dst, cursor, colarr);

    split_sep<<<(20480 + 255) / 256, 256, 0, stream>>>(Wl, Wlh, Wll, 20480);
    split_sep<<<(20480 + 255) / 256, 256, 0, stream>>>(Wr, Wrh, Wrl, 20480);
    split_pk<<<(1638400 + 255) / 256, 256, 0, stream>>>(x, h_pk, 1638400);

    for (int l = 0; l < N_LAYERS; ++l) {
        aggregate_pk<<<(N_NODES + 3) / 4, 256, 0, stream>>>(
            h_pk, row_ptr, colarr, deg_inv, mean_pk);
        gemm_mfma<<<(N_NODES + 255) / 256, 512, 0, stream>>>(
            mean_pk, h_pk,
            Wlh + (size_t)l * 16384, Wll + (size_t)l * 16384,
            Wrh + (size_t)l * 16384, Wrl + (size_t)l * 16384,
            bias + (size_t)l * HID,
            h_pk, out, (l == N_LAYERS - 1) ? 1 : 0);
    }
}

// Round 5
// 402.902 us; speedup vs baseline: 2.2438x; 1.0231x over previous
//
#include <hip/hip_runtime.h>

#define N_NODES 50000
#define N_EDGES 600000
#define HID 128
#define N_LAYERS 5
#define SCAN_BLK 256
#define N_SCAN_BLOCKS ((N_NODES + SCAN_BLK - 1) / SCAN_BLK)   // 196
#define NH ((size_t)N_NODES * HID)

typedef unsigned int u32;
typedef _Float16 half8 __attribute__((ext_vector_type(8)));
typedef _Float16 half4 __attribute__((ext_vector_type(4)));
typedef float f32x4 __attribute__((ext_vector_type(4)));
typedef u32 u32x8 __attribute__((ext_vector_type(8)));

// packed split format: one u32 per feature; h[0]=fp16 hi, h[1]=fp16 residual
union PK { u32 u; _Float16 h[2]; };

__device__ inline u32 pack_split(float v) {
    PK r;
    r.h[0] = (_Float16)v;
    r.h[1] = (_Float16)(v - (float)r.h[0]);
    return r.u;
}
__device__ inline float unpack_sum(u32 p) {
    PK r; r.u = p;
    return (float)r.h[0] + (float)r.h[1];
}

// ---------------- CSR build ----------------

__global__ void deg_count(const int* __restrict__ dst, int* __restrict__ deg) {
    int e = blockIdx.x * blockDim.x + threadIdx.x;
    if (e < N_EDGES) atomicAdd(&deg[dst[e]], 1);
}

__global__ __launch_bounds__(SCAN_BLK) void deg_reduce(const int* __restrict__ deg,
                                                       int* __restrict__ block_sums) {
    __shared__ int s[SCAN_BLK];
    int i = blockIdx.x * SCAN_BLK + threadIdx.x;
    int v = (i < N_NODES) ? deg[i] : 0;
    s[threadIdx.x] = v;
    __syncthreads();
    for (int off = SCAN_BLK / 2; off > 0; off >>= 1) {
        if (threadIdx.x < off) s[threadIdx.x] += s[threadIdx.x + off];
        __syncthreads();
    }
    if (threadIdx.x == 0) block_sums[blockIdx.x] = s[0];
}

__global__ __launch_bounds__(SCAN_BLK) void scan_partials(const int* __restrict__ block_sums,
                                                          int* __restrict__ block_off) {
    __shared__ int s[SCAN_BLK];
    int t = threadIdx.x;
    int v = (t < N_SCAN_BLOCKS) ? block_sums[t] : 0;
    s[t] = v;
    __syncthreads();
    for (int off = 1; off < SCAN_BLK; off <<= 1) {
        int u = (t >= off) ? s[t - off] : 0;
        __syncthreads();
        s[t] += u;
        __syncthreads();
    }
    if (t < N_SCAN_BLOCKS) block_off[t] = s[t] - v;
}

__global__ __launch_bounds__(SCAN_BLK) void scan_write(const int* __restrict__ deg,
        const int* __restrict__ block_off, int* __restrict__ row_ptr,
        int* __restrict__ cursor, float* __restrict__ deg_inv) {
    __shared__ int s[SCAN_BLK];
    int t = threadIdx.x;
    int i = blockIdx.x * SCAN_BLK + t;
    int v = (i < N_NODES) ? deg[i] : 0;
    s[t] = v;
    __syncthreads();
    for (int off = 1; off < SCAN_BLK; off <<= 1) {
        int u = (t >= off) ? s[t - off] : 0;
        __syncthreads();
        s[t] += u;
        __syncthreads();
    }
    int excl = s[t] - v + block_off[blockIdx.x];
    if (i < N_NODES) {
        row_ptr[i] = excl;
        cursor[i]  = excl;
        deg_inv[i] = 1.0f / (float)max(v, 1);
    }
    if (i == N_NODES) row_ptr[N_NODES] = excl;
}

__global__ void fill_csr(const int* __restrict__ src, const int* __restrict__ dst,
                         int* __restrict__ cursor, int* __restrict__ col) {
    int e = blockIdx.x * blockDim.x + threadIdx.x;
    if (e < N_EDGES) {
        int d = dst[e];
        int pos = atomicAdd(&cursor[d], 1);
        col[pos] = src[e];
    }
}

// ---------------- splits ----------------

__global__ void split_sep(const float* __restrict__ src,
                          _Float16* __restrict__ hi, _Float16* __restrict__ lo, int n4) {
    int i = blockIdx.x * blockDim.x + threadIdx.x;
    if (i >= n4) return;
    float4 v = *(const float4*)(src + (size_t)i * 4);
    half4 h, l;
    h.x = (_Float16)v.x; l.x = (_Float16)(v.x - (float)h.x);
    h.y = (_Float16)v.y; l.y = (_Float16)(v.y - (float)h.y);
    h.z = (_Float16)v.z; l.z = (_Float16)(v.z - (float)h.z);
    h.w = (_Float16)v.w; l.w = (_Float16)(v.w - (float)h.w);
    *(half4*)(hi + (size_t)i * 4) = h;
    *(half4*)(lo + (size_t)i * 4) = l;
}

__global__ void split_pk(const float* __restrict__ src, u32* __restrict__ dst, int n4) {
    int i = blockIdx.x * blockDim.x + threadIdx.x;
    if (i >= n4) return;
    float4 v = *(const float4*)(src + (size_t)i * 4);
    uint4 r;
    r.x = pack_split(v.x); r.y = pack_split(v.y);
    r.z = pack_split(v.z); r.w = pack_split(v.w);
    *(uint4*)(dst + (size_t)i * 4) = r;
}

// ---- mean aggregation: wave per node, half-wave edge slots, 16B/lane gathers ----
// lane l: edge slot = l>>5, feature quad = (l&31)*4. Neighbor indices fetched
// 64-at-a-time coalesced, distributed via __shfl (no per-edge scalar loads).

__global__ __launch_bounds__(256) void aggregate_w64(const u32* __restrict__ hp,
        const int* __restrict__ row_ptr, const int* __restrict__ col,
        const float* __restrict__ deg_inv, u32* __restrict__ mp) {
    int wave = threadIdx.x >> 6;
    int lane = threadIdx.x & 63;
    int node = blockIdx.x * 4 + wave;
    if (node >= N_NODES) return;
    int beg = row_ptr[node], end = row_ptr[node + 1];
    int deg = end - beg;
    const int slot = lane >> 5;          // 0/1: which edge this half-wave takes
    const int fo   = (lane & 31) * 4;    // feature-quad offset (16B granule)
    float a0 = 0.f, a1 = 0.f, a2 = 0.f, a3 = 0.f;

    for (int base = 0; base < deg; base += 64) {
        int cnt = deg - base; if (cnt > 64) cnt = 64;
        int p = beg + base + lane;
        int ci = col[(p < end) ? p : (end - 1)];   // coalesced chunk of neighbor ids
        int e = 0;
        for (; e + 3 < cnt; e += 4) {              // 4 edges in flight per iter
            int s0 = __shfl(ci, e + slot, 64);
            int s1 = __shfl(ci, e + 2 + slot, 64);
            uint4 v0 = *(const uint4*)(hp + (size_t)s0 * HID + fo);
            uint4 v1 = *(const uint4*)(hp + (size_t)s1 * HID + fo);
            a0 += unpack_sum(v0.x) + unpack_sum(v1.x);
            a1 += unpack_sum(v0.y) + unpack_sum(v1.y);
            a2 += unpack_sum(v0.z) + unpack_sum(v1.z);
            a3 += unpack_sum(v0.w) + unpack_sum(v1.w);
        }
        for (; e < cnt; e += 2) {                  // tail (0-3 edges)
            int idx = e + slot;
            int s0 = __shfl(ci, (idx < cnt) ? idx : 0, 64);
            if (idx < cnt) {
                uint4 v0 = *(const uint4*)(hp + (size_t)s0 * HID + fo);
                a0 += unpack_sum(v0.x);
                a1 += unpack_sum(v0.y);
                a2 += unpack_sum(v0.z);
                a3 += unpack_sum(v0.w);
            }
        }
    }
    a0 += __shfl_xor(a0, 32, 64);
    a1 += __shfl_xor(a1, 32, 64);
    a2 += __shfl_xor(a2, 32, 64);
    a3 += __shfl_xor(a3, 32, 64);
    if (lane < 32) {
        float di = deg_inv[node];
        uint4 r;
        r.x = pack_split(a0 * di);
        r.y = pack_split(a1 * di);
        r.z = pack_split(a2 * di);
        r.w = pack_split(a3 * di);
        *(uint4*)(mp + (size_t)node * HID + fo) = r;
    }
}

// ---------------- MFMA GEMM (packed A operands) ----------------

__device__ inline void unpk8(u32x8 p, half8& hi, half8& lo) {
    #pragma unroll
    for (int i = 0; i < 8; ++i) {
        PK t; t.u = p[i];
        hi[i] = t.h[0];
        lo[i] = t.h[1];
    }
}

__global__ __launch_bounds__(512, 2) void gemm_mfma(
        const u32* __restrict__ mean_pk, const u32* __restrict__ h_pk,
        const _Float16* __restrict__ Wlh, const _Float16* __restrict__ Wll,
        const _Float16* __restrict__ Wrh, const _Float16* __restrict__ Wrl,
        const float* __restrict__ bias,
        u32* __restrict__ out_pk, float* __restrict__ out_f32, int final_layer) {
    __shared__ char Wlds[131072];          // [4 mats][128 j][128 k] fp16, swizzled
    const int t    = threadIdx.x;
    const int lane = t & 63;
    const int w    = t >> 6;
    const int jr   = lane & 15;
    const int q    = lane >> 4;

    #pragma unroll
    for (int i = 0; i < 4; ++i) {
        int gi = t + i * 512;
        int j = gi >> 4, p = gi & 15;
        int dstb = j * 256 + (p ^ (j & 7)) * 16;
        int srci = j * HID + p * 8;
        *(half8*)&Wlds[0 * 32768 + dstb] = *(const half8*)(Wlh + srci);
        *(half8*)&Wlds[1 * 32768 + dstb] = *(const half8*)(Wll + srci);
        *(half8*)&Wlds[2 * 32768 + dstb] = *(const half8*)(Wrh + srci);
        *(half8*)&Wlds[3 * 32768 + dstb] = *(const half8*)(Wrl + srci);
    }
    __syncthreads();

    const int base0 = blockIdx.x * 256 + w * 32;
    int r0 = base0 + jr;      if (r0 > N_NODES - 1) r0 = N_NODES - 1;
    int r1 = base0 + 16 + jr; if (r1 > N_NODES - 1) r1 = N_NODES - 1;
    const int ko = q * 8;

    f32x4 acc0[8], acc1[8];
    #pragma unroll
    for (int jt = 0; jt < 8; ++jt) {
        acc0[jt] = (f32x4)(0.f);
        acc1[jt] = (f32x4)(0.f);
    }

    #pragma unroll 2
    for (int kk = 0; kk < 4; ++kk) {
        const size_t a0 = (size_t)r0 * HID + kk * 32 + ko;
        const size_t a1 = (size_t)r1 * HID + kk * 32 + ko;
        u32x8 mp0 = *(const u32x8*)(mean_pk + a0);
        u32x8 hp0 = *(const u32x8*)(h_pk   + a0);
        u32x8 mp1 = *(const u32x8*)(mean_pk + a1);
        u32x8 hp1 = *(const u32x8*)(h_pk   + a1);
        half8 mh0, ml0, hh0, hl0, mh1, ml1, hh1, hl1;
        unpk8(mp0, mh0, ml0); unpk8(hp0, hh0, hl0);
        unpk8(mp1, mh1, ml1); unpk8(hp1, hh1, hl1);
        #pragma unroll
        for (int jt = 0; jt < 8; ++jt) {
            int j  = jt * 16 + jr;
            int wb = j * 256 + (((kk * 4 + q) ^ (j & 7)) * 16);
            half8 wlh = *(const half8*)&Wlds[0 * 32768 + wb];
            half8 wll = *(const half8*)&Wlds[1 * 32768 + wb];
            half8 wrh = *(const half8*)&Wlds[2 * 32768 + wb];
            half8 wrl = *(const half8*)&Wlds[3 * 32768 + wb];
            acc0[jt] = __builtin_amdgcn_mfma_f32_16x16x32_f16(mh0, wlh, acc0[jt], 0, 0, 0);
            acc0[jt] = __builtin_amdgcn_mfma_f32_16x16x32_f16(ml0, wlh, acc0[jt], 0, 0, 0);
            acc0[jt] = __builtin_amdgcn_mfma_f32_16x16x32_f16(mh0, wll, acc0[jt], 0, 0, 0);
            acc0[jt] = __builtin_amdgcn_mfma_f32_16x16x32_f16(hh0, wrh, acc0[jt], 0, 0, 0);
            acc0[jt] = __builtin_amdgcn_mfma_f32_16x16x32_f16(hl0, wrh, acc0[jt], 0, 0, 0);
            acc0[jt] = __builtin_amdgcn_mfma_f32_16x16x32_f16(hh0, wrl, acc0[jt], 0, 0, 0);
            acc1[jt] = __builtin_amdgcn_mfma_f32_16x16x32_f16(mh1, wlh, acc1[jt], 0, 0, 0);
            acc1[jt] = __builtin_amdgcn_mfma_f32_16x16x32_f16(ml1, wlh, acc1[jt], 0, 0, 0);
            acc1[jt] = __builtin_amdgcn_mfma_f32_16x16x32_f16(mh1, wll, acc1[jt], 0, 0, 0);
            acc1[jt] = __builtin_amdgcn_mfma_f32_16x16x32_f16(hh1, wrh, acc1[jt], 0, 0, 0);
            acc1[jt] = __builtin_amdgcn_mfma_f32_16x16x32_f16(hl1, wrh, acc1[jt], 0, 0, 0);
            acc1[jt] = __builtin_amdgcn_mfma_f32_16x16x32_f16(hh1, wrl, acc1[jt], 0, 0, 0);
        }
    }

    float bv[8];
    #pragma unroll
    for (int jt = 0; jt < 8; ++jt) bv[jt] = bias[jt * 16 + jr];

    #pragma unroll
    for (int jt = 0; jt < 8; ++jt) {
        #pragma unroll
        for (int g = 0; g < 4; ++g) {
            int row = base0 + q * 4 + g;
            if (row < N_NODES) {
                float v = acc0[jt][g] + bv[jt];
                size_t idx = (size_t)row * HID + jt * 16 + jr;
                if (final_layer) out_f32[idx] = v;
                else             out_pk[idx] = pack_split(fmaxf(v, 0.f));
            }
            int row2 = base0 + 16 + q * 4 + g;
            if (row2 < N_NODES) {
                float v = acc1[jt][g] + bv[jt];
                size_t idx = (size_t)row2 * HID + jt * 16 + jr;
                if (final_layer) out_f32[idx] = v;
                else             out_pk[idx] = pack_split(fmaxf(v, 0.f));
            }
        }
    }
}

// ---------------- launch ----------------

extern "C" void kernel_launch(void* const* d_in, const int* in_sizes, int n_in,
                              void* d_out, int out_size, void* d_ws, size_t ws_size,
                              hipStream_t stream) {
    const float* x    = (const float*)d_in[0];
    const int*   edge = (const int*)d_in[1];
    const float* Wl   = (const float*)d_in[2];
    const float* Wr   = (const float*)d_in[3];
    const float* bias = (const float*)d_in[4];
    float* out = (float*)d_out;

    u32* h_pk    = (u32*)d_ws;                    // 25.6 MB
    u32* mean_pk = h_pk + NH;                     // 25.6 MB
    _Float16* Wlh = (_Float16*)(mean_pk + NH);    // 5*128*128 fp16 each
    _Float16* Wll = Wlh + 81920;
    _Float16* Wrh = Wll + 81920;
    _Float16* Wrl = Wrh + 81920;
    float* deg_inv = (float*)(Wrl + 81920);
    int*   deg     = (int*)(deg_inv + N_NODES);
    int*   row_ptr = deg + N_NODES;
    int*   cursor  = row_ptr + (N_NODES + 1);
    int*   colarr  = cursor + N_NODES;
    int*   blk_sums = colarr + N_EDGES;
    int*   blk_off  = blk_sums + N_SCAN_BLOCKS;

    const int* src = edge;
    const int* dst = edge + N_EDGES;

    hipMemsetAsync(deg, 0, N_NODES * sizeof(int), stream);
    deg_count<<<(N_EDGES + 255) / 256, 256, 0, stream>>>(dst, deg);
    deg_reduce<<<N_SCAN_BLOCKS, SCAN_BLK, 0, stream>>>(deg, blk_sums);
    scan_partials<<<1, SCAN_BLK, 0, stream>>>(blk_sums, blk_off);
    scan_write<<<N_SCAN_BLOCKS, SCAN_BLK, 0, stream>>>(deg, blk_off, row_ptr,
                                                       cursor, deg_inv);
    fill_csr<<<(N_EDGES + 255) / 256, 256, 0, stream>>>(src, dst, cursor, colarr);

    split_sep<<<(20480 + 255) / 256, 256, 0, stream>>>(Wl, Wlh, Wll, 20480);
    split_sep<<<(20480 + 255) / 256, 256, 0, stream>>>(Wr, Wrh, Wrl, 20480);
    split_pk<<<(1638400 + 255) / 256, 256, 0, stream>>>(x, h_pk, 1638400);

    for (int l = 0; l < N_LAYERS; ++l) {
        aggregate_w64<<<(N_NODES + 3) / 4, 256, 0, stream>>>(
            h_pk, row_ptr, colarr, deg_inv, mean_pk);
        gemm_mfma<<<(N_NODES + 255) / 256, 512, 0, stream>>>(
            mean_pk, h_pk,
            Wlh + (size_t)l * 16384, Wll + (size_t)l * 16384,
            Wrh + (size_t)l * 16384, Wrl + (size_t)l * 16384,
            bias + (size_t)l * HID,
            h_pk, out, (l == N_LAYERS - 1) ? 1 : 0);
    }
}